// Round 7
// baseline (1179.195 us; speedup 1.0000x reference)
//
#include <hip/hip_runtime.h>

// Seq2SeqRNN v12: serial-chain shortening on the v10 base (902us dispatch).
//  (1) double-buffered XH (v7-proven parity logic): 1 barrier/enc step (was 2),
//      2/dec step (was 3) -- staging + h-writes to [sg&1] before one end bar.
//  (2) decoder bubble folded: dec (waves 0-3) -> gates c2..c10 (fb-independent,
//      54 MFMAs) -> lgkm bar (fb long committed, ~free) -> gates c0,c1 -> ptwise.
//  (3) readfirstlane SGPR stream bases + imm offsets: per-step stream addr VALU=0.
// Kept: A-hoist single k-pass, rcp/exp2, frag-linear images, reg input prefetch.
// v11 lesson: vmcnt drains were NOT the cost; barrier count / phase order is.

#define BATCH 512
#define TSEQ  192
#define LIN_  96
#define LOUT_ 96
#define NUM_  64
#define EMB_  32
#define HID_  256
#define INS_  96

#define NBLK  32
#define NT    512          // 8 waves, 2/SIMD
// XH row (us cols): [num0 64 | num1 64 | e0 32 | e1 32 | h0 256 | h1 256] = 704
#define XSTR  712
#define XEMB0 128
#define XHB   192          // h0 @192, h1 @448

// ws: fragment-linear bf16 images (1024 B per frag; lane l -> bytes l*16..+16)
//  WL (LDS-staged): fid = g*32 + tt*2 + cs   (g<3, tt<16, cs<2 -> chunk 6+cs)  96 frags
//  WS (streamed)  : fid = g*48 + tt*3 + cs   (cs<3 -> chunk 8+cs)             144 frags
//  WD (W_dec)     : fid = tt*8 + c           (tt<4, c<8)                       32 frags
#define WS_WL   0u
#define WS_WS   98304u
#define WS_WD   245760u
#define WS_NEED 278528u

typedef __attribute__((ext_vector_type(8))) short short8_t;
typedef __attribute__((ext_vector_type(4))) float float4_t;
typedef unsigned short us;

__device__ __forceinline__ us f2bf(float x) {
    unsigned u = __builtin_bit_cast(unsigned, x);
    u = (u + 0x7FFFu + ((u >> 16) & 1u)) >> 16;
    return (us)u;
}
__device__ __forceinline__ float sigm(float x) {
    return __builtin_amdgcn_rcpf(1.0f + __builtin_amdgcn_exp2f(-1.44269504f * x));
}
__device__ __forceinline__ float tanhx(float x) {
    return 2.0f * __builtin_amdgcn_rcpf(1.0f + __builtin_amdgcn_exp2f(-2.88539008f * x)) - 1.0f;
}

// lgkm-only barrier: LDS visibility without draining global loads/stores.
__device__ __forceinline__ void bar_lds() {
    __builtin_amdgcn_sched_barrier(0);
    asm volatile("s_waitcnt lgkmcnt(0)" ::: "memory");
    __builtin_amdgcn_s_barrier();
    __builtin_amdgcn_sched_barrier(0);
}

__device__ __forceinline__ short8_t pack8(const float* v) {
    short8_t s;
    #pragma unroll
    for (int j = 0; j < 8; ++j) s[j] = (short)f2bf(v[j]);
    return s;
}

#define MFMA16(a, b, c) __builtin_amdgcn_mfma_f32_16x16x32_bf16((a), (b), (c), 0, 0, 0)

// ============ prep: fragment-linear bf16 weight images (v10-identical) ============
__global__ void prep_v12(const float* __restrict__ W_hh, const float* __restrict__ W_dec,
                         unsigned char* __restrict__ ws) {
    us* WLi = (us*)(ws + WS_WL);
    us* WSi = (us*)(ws + WS_WS);
    us* WDi = (us*)(ws + WS_WD);
    const int idx = blockIdx.x * 256 + threadIdx.x;
    if (idx >= 272 * 64) return;
    const int f = idx >> 6, l = idx & 63;
    const int r16 = l & 15, kq8 = (l >> 4) * 8;
    float tmp[8];
    if (f < 96) {                  // WL: chunks 6,7 (k 192..255, all W_hh)
        const int g = f >> 5, rem = f & 31, tt = rem >> 1, cs = rem & 1;
        const int grow = g * 256 + tt * 16 + r16;
        const int k = (6 + cs) * 32 + kq8;
        #pragma unroll
        for (int j = 0; j < 8; ++j) tmp[j] = W_hh[(size_t)grow * HID_ + (k - INS_) + j];
        *(short8_t*)(WLi + (size_t)f * 512 + l * 8) = pack8(tmp);
    } else if (f < 240) {          // WS: chunks 8,9,10 (k 256..351, all W_hh)
        const int s = f - 96, g = s / 48, rem = s % 48, tt = rem / 3, cs = rem % 3;
        const int grow = g * 256 + tt * 16 + r16;
        const int k = (8 + cs) * 32 + kq8;
        #pragma unroll
        for (int j = 0; j < 8; ++j) tmp[j] = W_hh[(size_t)grow * HID_ + (k - INS_) + j];
        *(short8_t*)(WSi + (size_t)s * 512 + l * 8) = pack8(tmp);
    } else {                       // WD
        const int f3 = f - 240, tt = f3 >> 3, c = f3 & 7;
        const int urow = tt * 16 + r16, k = c * 32 + kq8;
        #pragma unroll
        for (int j = 0; j < 8; ++j) tmp[j] = W_dec[(size_t)urow * HID_ + k + j];
        *(short8_t*)(WDi + (size_t)f3 * 512 + l * 8) = pack8(tmp);
    }
}

// ============ main: one self-sufficient block per 16 batch rows ============
__global__ __launch_bounds__(NT, 2) void gru_v12(
    const float* __restrict__ input_num, const int* __restrict__ input_cat,
    const float* __restrict__ emb_table,
    const float* __restrict__ W_ih, const float* __restrict__ W_hh,
    const float* __restrict__ b_ih, const float* __restrict__ b_hh,
    const float* __restrict__ b_dec,
    const unsigned char* __restrict__ ws, float* __restrict__ out)
{
    __shared__ __align__(16) us XH[16 * XSTR];     // 22.25 KB (double-buffered)
    __shared__ __align__(16) us WLl[96 * 512];     // 96 KB (chunks 6,7)
    __shared__ __align__(16) us WDl[32 * 512];     // 32 KB (W_dec)

    const us* WSf = (const us*)(ws + WS_WS);

    const int t = threadIdx.x, wave = t >> 6, lane = t & 63;
    const int arow = lane & 15, quad = lane >> 4, kq = quad * 8;
    const int bb = blockIdx.x * 16;
    const int tt0 = 2 * wave, tt1 = 2 * wave + 1;

    // ---- one-time: reg gate-weight frags, chunks 0..5 (144 regs, proven) ----
    short8_t wfr[2][3][6];
    #pragma unroll
    for (int ti = 0; ti < 2; ++ti) {
        #pragma unroll
        for (int g3 = 0; g3 < 3; ++g3) {
            const int grow = g3 * HID_ + 32 * wave + 16 * ti + arow;
            #pragma unroll
            for (int kc = 0; kc < 6; ++kc) {
                float tmp[8];
                #pragma unroll
                for (int j2 = 0; j2 < 2; ++j2) {
                    const int k = kc * 32 + kq + j2 * 4;   // < 192; never straddles 96
                    float4 v = (k < INS_)
                        ? *(const float4*)&W_ih[(size_t)grow * INS_ + k]
                        : *(const float4*)&W_hh[(size_t)grow * HID_ + (k - INS_)];
                    tmp[j2 * 4 + 0] = v.x; tmp[j2 * 4 + 1] = v.y;
                    tmp[j2 * 4 + 2] = v.z; tmp[j2 * 4 + 3] = v.w;
                }
                wfr[ti][g3][kc] = pack8(tmp);
            }
        }
    }

    // ---- one-time: LDS staging (fragment-linear copies) + XH zero ----
    {
        const us* WLi = (const us*)(ws + WS_WL);
        const us* WDi = (const us*)(ws + WS_WD);
        for (int c = t; c < 96 * 64; c += NT)
            *(ulonglong2*)&WLl[c * 8] = *(const ulonglong2*)&WLi[c * 8];
        for (int c = t; c < 32 * 64; c += NT)
            *(ulonglong2*)&WDl[c * 8] = *(const ulonglong2*)&WDi[c * 8];
        for (int c = t; c < 16 * XSTR; c += NT) XH[c] = 0;
    }

    // ---- biases (unit u = 32w + 16ti + arow) ----
    float bRr[2], bZr[2], bNXr[2], bNHr[2];
    #pragma unroll
    for (int ti = 0; ti < 2; ++ti) {
        const int u = 32 * wave + 16 * ti + arow;
        bRr[ti]  = b_ih[u] + b_hh[u];
        bZr[ti]  = b_ih[HID_ + u] + b_hh[HID_ + u];
        bNXr[ti] = b_ih[2 * HID_ + u];
        bNHr[ti] = b_hh[2 * HID_ + u];
    }
    const float bdr = (wave < 4) ? b_dec[wave * 16 + arow] : 0.0f;
    float hr[2][4] = {{0.f,0.f,0.f,0.f},{0.f,0.f,0.f,0.f}};

    // ---- SGPR stream base offsets (wave-uniform, forced scalar) ----
    unsigned sbase[6];   // [g*2 + ti]
    #pragma unroll
    for (int g = 0; g < 3; ++g) {
        sbase[g * 2 + 0] = __builtin_amdgcn_readfirstlane((unsigned)((g * 48 + tt0 * 3) * 1024));
        sbase[g * 2 + 1] = __builtin_amdgcn_readfirstlane((unsigned)((g * 48 + tt1 * 3) * 1024));
    }
    const char* WSbase = (const char*)WSf + (size_t)lane * 16;

    // ---- prefetch roles + prologue: stage timestep 0 -> parity 0; prefetch t=1 ----
    const int srow = t >> 4, sq = t & 15;                    // num role: t<256
    const int erow = (t - 256) >> 3, eq = (t - 256) & 7;     // emb role: 256<=t<384
    const bool isN = (t < 256), isE = (t >= 256 && t < 384);
    float4 pnum = {0.f,0.f,0.f,0.f}, pemb = {0.f,0.f,0.f,0.f};
    int pcat = 0;
    if (isN) {
        float4 v = *(const float4*)&input_num[((size_t)(bb + srow) * TSEQ + 0) * NUM_ + sq * 4];
        ushort4 s = { f2bf(v.x), f2bf(v.y), f2bf(v.z), f2bf(v.w) };
        *(ushort4*)&XH[srow * XSTR + sq * 4] = s;                          // numslot[0]
        pnum = *(const float4*)&input_num[((size_t)(bb + srow) * TSEQ + 1) * NUM_ + sq * 4];
    } else if (isE) {
        const int c0 = input_cat[(bb + erow) * TSEQ + 0];
        float4 v = *(const float4*)&emb_table[(size_t)c0 * EMB_ + eq * 4];
        ushort4 s = { f2bf(v.x), f2bf(v.y), f2bf(v.z), f2bf(v.w) };
        *(ushort4*)&XH[erow * XSTR + XEMB0 + eq * 4] = s;                  // embslot[0]
        const int c1 = input_cat[(bb + erow) * TSEQ + 1];
        pemb = *(const float4*)&emb_table[(size_t)c1 * EMB_ + eq * 4];
        pcat = input_cat[(bb + erow) * TSEQ + 2];
    }
    __syncthreads();

    // ======== 191 sequential GRU steps ========
    for (int sg = 1; sg <= 191; ++sg) {
        const int bx = (sg - 1) & 1, hn = sg & 1;
        const int hb = XHB + bx * 256;     // h_{sg-1}

        // issue stream chunks 8,9 (SGPR base + imm offset; zero per-step VALU)
        short8_t s8[6], s9[6];
        #pragma unroll
        for (int i = 0; i < 6; ++i) {
            s8[i] = *(const short8_t*)(WSbase + sbase[i]);
            s9[i] = *(const short8_t*)(WSbase + sbase[i] + 1024);
        }

        // decode: dec projection + fb write + out store (waves 0-3), NO barrier yet
        if (sg > 96 && wave < 4) {
            float4_t acc = {0.f, 0.f, 0.f, 0.f};
            #pragma unroll
            for (int c = 0; c < 8; ++c) {
                short8_t b = *(const short8_t*)&WDl[(wave * 8 + c) * 512 + lane * 8];
                short8_t a = *(const short8_t*)&XH[arow * XSTR + hb + c * 32 + kq];
                acc = MFMA16(a, b, acc);
            }
            const int cg = wave * 16 + arow, pos = sg - 97;
            #pragma unroll
            for (int i = 0; i < 4; ++i) {
                const int row = quad * 4 + i;
                const float val = acc[i] + bdr;
                XH[row * XSTR + bx * 64 + cg] = f2bf(val);   // fb -> numslot[bx]
                out[((size_t)(bb + row) * LOUT_ + pos) * NUM_ + cg] = val;
            }
        }

        // ---- gates part 1: chunks c2..c10 (fb-independent) ----
        float4_t aR[2]  = {{0.f,0.f,0.f,0.f},{0.f,0.f,0.f,0.f}};
        float4_t aZ[2]  = {{0.f,0.f,0.f,0.f},{0.f,0.f,0.f,0.f}};
        float4_t aNX[2] = {{0.f,0.f,0.f,0.f},{0.f,0.f,0.f,0.f}};
        float4_t aNH[2] = {{0.f,0.f,0.f,0.f},{0.f,0.f,0.f,0.f}};
        short8_t a;

        // c2: emb (reg weights)
        a = *(const short8_t*)&XH[arow * XSTR + XEMB0 + bx * 32 + kq];
        #pragma unroll
        for (int ti = 0; ti < 2; ++ti) {
            aR[ti] = MFMA16(a, wfr[ti][0][2], aR[ti]);
            aZ[ti] = MFMA16(a, wfr[ti][1][2], aZ[ti]);
            aNX[ti] = MFMA16(a, wfr[ti][2][2], aNX[ti]);
        }
        // c3..c5: h (reg weights)
        #pragma unroll
        for (int kc = 3; kc < 6; ++kc) {
            a = *(const short8_t*)&XH[arow * XSTR + hb + (kc - 3) * 32 + kq];
            #pragma unroll
            for (int ti = 0; ti < 2; ++ti) {
                aR[ti] = MFMA16(a, wfr[ti][0][kc], aR[ti]);
                aZ[ti] = MFMA16(a, wfr[ti][1][kc], aZ[ti]);
                aNH[ti] = MFMA16(a, wfr[ti][2][kc], aNH[ti]);
            }
        }
        // c6,c7: LDS (fragment-linear)
        #pragma unroll
        for (int cs = 0; cs < 2; ++cs) {
            a = *(const short8_t*)&XH[arow * XSTR + hb + (3 + cs) * 32 + kq];
            #pragma unroll
            for (int ti = 0; ti < 2; ++ti) {
                const int tt = tt0 + ti;
                short8_t b0 = *(const short8_t*)&WLl[(0 * 32 + tt * 2 + cs) * 512 + lane * 8];
                short8_t b1 = *(const short8_t*)&WLl[(1 * 32 + tt * 2 + cs) * 512 + lane * 8];
                short8_t b2 = *(const short8_t*)&WLl[(2 * 32 + tt * 2 + cs) * 512 + lane * 8];
                aR[ti] = MFMA16(a, b0, aR[ti]);
                aZ[ti] = MFMA16(a, b1, aZ[ti]);
                aNH[ti] = MFMA16(a, b2, aNH[ti]);
            }
        }
        // issue stream chunk 10
        short8_t s10[6];
        #pragma unroll
        for (int i = 0; i < 6; ++i)
            s10[i] = *(const short8_t*)(WSbase + sbase[i] + 2048);
        // c8,c9,c10: consume streamed frags
        a = *(const short8_t*)&XH[arow * XSTR + hb + 5 * 32 + kq];
        #pragma unroll
        for (int ti = 0; ti < 2; ++ti) {
            aR[ti] = MFMA16(a, s8[0 * 2 + ti], aR[ti]);
            aZ[ti] = MFMA16(a, s8[1 * 2 + ti], aZ[ti]);
            aNH[ti] = MFMA16(a, s8[2 * 2 + ti], aNH[ti]);
        }
        a = *(const short8_t*)&XH[arow * XSTR + hb + 6 * 32 + kq];
        #pragma unroll
        for (int ti = 0; ti < 2; ++ti) {
            aR[ti] = MFMA16(a, s9[0 * 2 + ti], aR[ti]);
            aZ[ti] = MFMA16(a, s9[1 * 2 + ti], aZ[ti]);
            aNH[ti] = MFMA16(a, s9[2 * 2 + ti], aNH[ti]);
        }
        a = *(const short8_t*)&XH[arow * XSTR + hb + 7 * 32 + kq];
        #pragma unroll
        for (int ti = 0; ti < 2; ++ti) {
            aR[ti] = MFMA16(a, s10[0 * 2 + ti], aR[ti]);
            aZ[ti] = MFMA16(a, s10[1 * 2 + ti], aZ[ti]);
            aNH[ti] = MFMA16(a, s10[2 * 2 + ti], aNH[ti]);
        }

        // B2 (decode only): fb visible -- fb ds_writes committed long ago
        if (sg > 96) bar_lds();

        // ---- gates part 2: chunks c0,c1 (num or fb) ----
        a = *(const short8_t*)&XH[arow * XSTR + bx * 64 + kq];
        #pragma unroll
        for (int ti = 0; ti < 2; ++ti) {
            aR[ti] = MFMA16(a, wfr[ti][0][0], aR[ti]);
            aZ[ti] = MFMA16(a, wfr[ti][1][0], aZ[ti]);
            aNX[ti] = MFMA16(a, wfr[ti][2][0], aNX[ti]);
        }
        a = *(const short8_t*)&XH[arow * XSTR + bx * 64 + 32 + kq];
        #pragma unroll
        for (int ti = 0; ti < 2; ++ti) {
            aR[ti] = MFMA16(a, wfr[ti][0][1], aR[ti]);
            aZ[ti] = MFMA16(a, wfr[ti][1][1], aZ[ti]);
            aNX[ti] = MFMA16(a, wfr[ti][2][1], aNX[ti]);
        }

        // ---- pointwise (rcp/exp2) ----
        #pragma unroll
        for (int ti = 0; ti < 2; ++ti) {
            #pragma unroll
            for (int i = 0; i < 4; ++i) {
                const float r = sigm(aR[ti][i] + bRr[ti]);
                const float z = sigm(aZ[ti][i] + bZr[ti]);
                const float n = tanhx(aNX[ti][i] + bNXr[ti] + r * (aNH[ti][i] + bNHr[ti]));
                hr[ti][i] = (1.0f - z) * n + z * hr[ti][i];
            }
        }

        // ---- end of step: h[hn] write + stage timestep sg -> parity hn + prefetch ----
        #pragma unroll
        for (int ti = 0; ti < 2; ++ti) {
            #pragma unroll
            for (int i = 0; i < 4; ++i)
                XH[(quad * 4 + i) * XSTR + XHB + hn * 256 + 32 * wave + 16 * ti + arow] = f2bf(hr[ti][i]);
        }
        if (sg <= 190) {
            if (isN) {
                if (sg <= 95) {
                    ushort4 s = { f2bf(pnum.x), f2bf(pnum.y), f2bf(pnum.z), f2bf(pnum.w) };
                    *(ushort4*)&XH[srow * XSTR + hn * 64 + sq * 4] = s;
                }
                if (sg <= 94)
                    pnum = *(const float4*)&input_num[((size_t)(bb + srow) * TSEQ + sg + 1) * NUM_ + sq * 4];
            } else if (isE) {
                ushort4 s = { f2bf(pemb.x), f2bf(pemb.y), f2bf(pemb.z), f2bf(pemb.w) };
                *(ushort4*)&XH[erow * XSTR + XEMB0 + hn * 32 + eq * 4] = s;
                if (sg <= 189) {
                    pemb = *(const float4*)&emb_table[(size_t)pcat * EMB_ + eq * 4];
                    if (sg <= 188) pcat = input_cat[(bb + erow) * TSEQ + sg + 2];
                }
            }
        }
        bar_lds();   // single end-of-step barrier
    }

    // ======== epilogue: out position 95 from h_191 (h buf 1) ========
    if (wave < 4) {
        float4_t acc = {0.f, 0.f, 0.f, 0.f};
        #pragma unroll
        for (int c = 0; c < 8; ++c) {
            short8_t b = *(const short8_t*)&WDl[(wave * 8 + c) * 512 + lane * 8];
            short8_t a = *(const short8_t*)&XH[arow * XSTR + XHB + 256 + c * 32 + kq];
            acc = MFMA16(a, b, acc);
        }
        const int cg = wave * 16 + arow;
        #pragma unroll
        for (int i = 0; i < 4; ++i) {
            const int row = quad * 4 + i;
            out[((size_t)(bb + row) * LOUT_ + 95) * NUM_ + cg] = acc[i] + bdr;
        }
    }
}

// ============ fallback (v1 logic, known-passing fp32) if ws too small ============
__global__ __launch_bounds__(512) void gru_fallback(
    const float* __restrict__ input_num, const int* __restrict__ input_cat,
    const float* __restrict__ emb_table,
    const float* __restrict__ W_ih, const float* __restrict__ W_hh,
    const float* __restrict__ b_ih, const float* __restrict__ b_hh,
    const float* __restrict__ W_dec, const float* __restrict__ b_dec,
    float* __restrict__ out)
{
    __shared__ __align__(16) float xh[4][352];
    __shared__ float wdec[NUM_ * 257];
    const int t = threadIdx.x, bbase = blockIdx.x * 4;
    const int u = t & 255, rb = (t >> 8) * 2;
    for (int i = t; i < NUM_ * HID_; i += 512) wdec[(i >> 8) * 257 + (i & 255)] = W_dec[i];
    for (int i = t; i < 4 * HID_; i += 512) xh[i >> 8][INS_ + (i & 255)] = 0.0f;
    const float bR = b_ih[u] + b_hh[u], bZ = b_ih[256 + u] + b_hh[256 + u];
    const float bNX = b_ih[512 + u], bNH = b_hh[512 + u], bD = b_dec[t & 63];
    __syncthreads();
    auto sg_ = [](float x) { return 1.0f / (1.0f + __expf(-x)); };
    auto th_ = [](float x) { return 2.0f / (1.0f + __expf(-2.0f * x)) - 1.0f; };
    auto step = [&]() {
        float aR0 = bR, aR1 = bR, aZ0 = bZ, aZ1 = bZ, aNX0 = bNX, aNX1 = bNX, aNH0 = bNH, aNH1 = bNH;
        const float* x0 = xh[rb]; const float* x1 = xh[rb + 1];
        for (int kb = 0; kb < 88; ++kb) {
            float4 w0, w1, w2; int k4 = kb * 4;
            if (k4 < INS_) {
                w0 = *(const float4*)&W_ih[(size_t)u * INS_ + k4];
                w1 = *(const float4*)&W_ih[(size_t)(256 + u) * INS_ + k4];
                w2 = *(const float4*)&W_ih[(size_t)(512 + u) * INS_ + k4];
            } else {
                int kh = k4 - INS_;
                w0 = *(const float4*)&W_hh[(size_t)u * HID_ + kh];
                w1 = *(const float4*)&W_hh[(size_t)(256 + u) * HID_ + kh];
                w2 = *(const float4*)&W_hh[(size_t)(512 + u) * HID_ + kh];
            }
            float4 a = *(const float4*)&x0[k4], c = *(const float4*)&x1[k4];
            aR0 += w0.x*a.x+w0.y*a.y+w0.z*a.z+w0.w*a.w; aR1 += w0.x*c.x+w0.y*c.y+w0.z*c.z+w0.w*c.w;
            aZ0 += w1.x*a.x+w1.y*a.y+w1.z*a.z+w1.w*a.w; aZ1 += w1.x*c.x+w1.y*c.y+w1.z*c.z+w1.w*c.w;
            if (k4 < INS_) { aNX0 += w2.x*a.x+w2.y*a.y+w2.z*a.z+w2.w*a.w; aNX1 += w2.x*c.x+w2.y*c.y+w2.z*c.z+w2.w*c.w; }
            else           { aNH0 += w2.x*a.x+w2.y*a.y+w2.z*a.z+w2.w*a.w; aNH1 += w2.x*c.x+w2.y*c.y+w2.z*c.z+w2.w*c.w; }
        }
        float h0 = x0[INS_ + u], h1 = x1[INS_ + u];
        __syncthreads();
        { float r = sg_(aR0), z = sg_(aZ0), n = th_(aNX0 + r * aNH0);
          xh[rb][INS_ + u] = (1 - z) * n + z * h0; }
        { float r = sg_(aR1), z = sg_(aZ1), n = th_(aNX1 + r * aNH1);
          xh[rb + 1][INS_ + u] = (1 - z) * n + z * h1; }
        __syncthreads();
    };
    auto project = [&](int pos) {
        if (t < 256) {
            int r = t >> 6, m = t & 63;
            const float* wr = &wdec[m * 257]; const float* hr2 = &xh[r][INS_];
            float acc = bD;
            for (int k = 0; k < HID_; ++k) acc = fmaf(wr[k], hr2[k], acc);
            out[((size_t)(bbase + r) * LOUT_ + pos) * NUM_ + m] = acc;
            xh[r][m] = acc;
        }
    };
    for (int s = 0; s < LIN_; ++s) {
        if (t < 256) { int r = t >> 6, k = t & 63;
            xh[r][k] = input_num[((size_t)(bbase + r) * TSEQ + s) * NUM_ + k]; }
        if (t < 128) { int r = t >> 5, e = t & 31;
            xh[r][NUM_ + e] = emb_table[input_cat[(bbase + r) * TSEQ + s] * EMB_ + e]; }
        __syncthreads();
        step();
    }
    project(0);
    for (int s = 0; s < LOUT_ - 1; ++s) {
        if (t < 128) { int r = t >> 5, e = t & 31;
            xh[r][NUM_ + e] = emb_table[input_cat[(bbase + r) * TSEQ + LIN_ + s] * EMB_ + e]; }
        __syncthreads();
        step();
        project(s + 1);
    }
}

extern "C" void kernel_launch(void* const* d_in, const int* in_sizes, int n_in,
                              void* d_out, int out_size, void* d_ws, size_t ws_size,
                              hipStream_t stream) {
    const float* input_num = (const float*)d_in[0];
    const int*   input_cat = (const int*)d_in[1];
    const float* emb_table = (const float*)d_in[2];
    const float* W_ih      = (const float*)d_in[3];
    const float* W_hh      = (const float*)d_in[4];
    const float* b_ih      = (const float*)d_in[5];
    const float* b_hh      = (const float*)d_in[6];
    const float* W_dec     = (const float*)d_in[7];
    const float* b_dec     = (const float*)d_in[8];
    float* out = (float*)d_out;

    if (ws_size >= WS_NEED) {
        unsigned char* ws = (unsigned char*)d_ws;
        prep_v12<<<68, 256, 0, stream>>>(W_hh, W_dec, ws);
        gru_v12<<<NBLK, NT, 0, stream>>>(input_num, input_cat, emb_table,
                                         W_ih, W_hh, b_ih, b_hh, b_dec, ws, out);
    } else {
        gru_fallback<<<BATCH / 4, 512, 0, stream>>>(input_num, input_cat, emb_table,
                                                    W_ih, W_hh, b_ih, b_hh, W_dec, b_dec, out);
    }
}

// Round 8
// 1177.092 us; speedup vs baseline: 1.0018x; 1.0018x over previous
//
#include <hip/hip_runtime.h>

// Seq2SeqRNN v13: v10 base (902us, best) + stream diet via LDS re-tenanting.
//  Budget at ~1.2GHz sustained: step=5.7K cyc; stream-L1 2.3K (144KB/step @ 64B/cyc)
//  is the dominant term (matches v5/v6/v8 dose-response 15cyc/KB). So:
//  (1) encoder: WL = c6,c7,c8(all gates) 144KB LDS (WD not resident yet);
//      stream = c9,c10 only (96KB/step, -33%).
//  (2) boundary sg=96: WD built from fp32 W_dec into the c8-z,n WL slots
//      (exactly 32KB, dead in decode); decode stream = c8zn+c9,c10 (128KB/step).
//  (3) WL/WD/wfr built in-kernel from fp32 (one-time); ws = 128-frag image only.
//  (4) decode deferred fb barrier: dec-proj -> gates c2..c10 -> B2 -> c0,c1
//      (v12's one sound idea, now unconfounded: plain __syncthreads, XSTR=360).

#define BATCH 512
#define TSEQ  192
#define LIN_  96
#define LOUT_ 96
#define NUM_  64
#define EMB_  32
#define HID_  256
#define INS_  96

#define NBLK  32
#define NT    512          // 8 waves, 2/SIMD
#define XSTR  360          // us stride, XH[16][x(96)|h(256)] (v5/v10-proven)

// ws: stream image only, fragment-linear (1024 B per frag; lane l -> bytes l*16..+16)
//  fid: [c8z: 0..15 (tt)] [c8n: 16..31] [c9: 32+g*16+tt] [c10: 80+g*16+tt] = 128 frags
#define WS_NEED 131072u

typedef __attribute__((ext_vector_type(8))) short short8_t;
typedef __attribute__((ext_vector_type(4))) float float4_t;
typedef unsigned short us;

__device__ __forceinline__ us f2bf(float x) {
    unsigned u = __builtin_bit_cast(unsigned, x);
    u = (u + 0x7FFFu + ((u >> 16) & 1u)) >> 16;
    return (us)u;
}
__device__ __forceinline__ float sigm(float x) {
    return __builtin_amdgcn_rcpf(1.0f + __builtin_amdgcn_exp2f(-1.44269504f * x));
}
__device__ __forceinline__ float tanhx(float x) {
    return 2.0f * __builtin_amdgcn_rcpf(1.0f + __builtin_amdgcn_exp2f(-2.88539008f * x)) - 1.0f;
}

__device__ __forceinline__ short8_t pack8(const float* v) {
    short8_t s;
    #pragma unroll
    for (int j = 0; j < 8; ++j) s[j] = (short)f2bf(v[j]);
    return s;
}

#define MFMA16(a, b, c) __builtin_amdgcn_mfma_f32_16x16x32_bf16((a), (b), (c), 0, 0, 0)

// ============ prep: 128-frag stream image (c8 z,n + c9,c10 all gates) ============
__global__ void prep_v13(const float* __restrict__ W_hh, unsigned char* __restrict__ ws) {
    us* WSi = (us*)ws;
    const int idx = blockIdx.x * 256 + threadIdx.x;
    if (idx >= 128 * 64) return;
    const int f = idx >> 6, l = idx & 63;
    const int r16 = l & 15, kq8 = (l >> 4) * 8;
    int g3, ck, tt;
    if (f < 16)      { ck = 8; g3 = 1; tt = f; }
    else if (f < 32) { ck = 8; g3 = 2; tt = f - 16; }
    else { const int j = f - 32; ck = 9 + j / 48; const int rem = j % 48; g3 = rem / 16; tt = rem % 16; }
    const int grow = g3 * HID_ + tt * 16 + r16;
    const int k = ck * 32 + kq8;                 // 256..351 -> W_hh col k-96
    float tmp[8];
    #pragma unroll
    for (int j = 0; j < 8; ++j) tmp[j] = W_hh[(size_t)grow * HID_ + (k - INS_) + j];
    *(short8_t*)(WSi + (size_t)f * 512 + l * 8) = pack8(tmp);
}

// ============ main: one self-sufficient block per 16 batch rows ============
__global__ __launch_bounds__(NT, 2) void gru_v13(
    const float* __restrict__ input_num, const int* __restrict__ input_cat,
    const float* __restrict__ emb_table,
    const float* __restrict__ W_ih, const float* __restrict__ W_hh,
    const float* __restrict__ b_ih, const float* __restrict__ b_hh,
    const float* __restrict__ W_dec, const float* __restrict__ b_dec,
    const unsigned char* __restrict__ ws, float* __restrict__ out)
{
    __shared__ __align__(16) us XH[16 * XSTR];   // 11520 B
    __shared__ __align__(16) us WL[144 * 512];   // 147456 B: c6(0..47) c7(48..95) c8r(96..111)
                                                 // c8z(112..127) c8n(128..143); WD -> 112..143 at boundary
    const us* WSf = (const us*)ws;

    const int t = threadIdx.x, wave = t >> 6, lane = t & 63;
    const int arow = lane & 15, quad = lane >> 4, kq = quad * 8;
    const int bb = blockIdx.x * 16;
    const int tt0 = 2 * wave, tt1 = 2 * wave + 1;

    // ---- one-time: reg gate-weight frags, chunks 0..5 (v10-identical) ----
    short8_t wfr[2][3][6];
    #pragma unroll
    for (int ti = 0; ti < 2; ++ti) {
        #pragma unroll
        for (int g3 = 0; g3 < 3; ++g3) {
            const int grow = g3 * HID_ + 32 * wave + 16 * ti + arow;
            #pragma unroll
            for (int kc = 0; kc < 6; ++kc) {
                float tmp[8];
                #pragma unroll
                for (int j2 = 0; j2 < 2; ++j2) {
                    const int k = kc * 32 + kq + j2 * 4;   // < 192; never straddles 96
                    float4 v = (k < INS_)
                        ? *(const float4*)&W_ih[(size_t)grow * INS_ + k]
                        : *(const float4*)&W_hh[(size_t)grow * HID_ + (k - INS_)];
                    tmp[j2 * 4 + 0] = v.x; tmp[j2 * 4 + 1] = v.y;
                    tmp[j2 * 4 + 2] = v.z; tmp[j2 * 4 + 3] = v.w;
                }
                wfr[ti][g3][kc] = pack8(tmp);
            }
        }
    }

    // ---- one-time: WL build from fp32 W_hh (c6,c7,c8 r/z/n = 144 frags) ----
    for (int i = t; i < 144 * 64; i += NT) {
        const int f = i >> 6, l = i & 63;
        const int r16 = l & 15, kq8 = (l >> 4) * 8;
        int g3, ck;
        if (f < 48)      { g3 = f >> 4;        ck = 6; }
        else if (f < 96) { g3 = (f - 48) >> 4; ck = 7; }
        else             { g3 = (f - 96) >> 4; ck = 8; }
        const int tt = f & 15;
        const int grow = g3 * HID_ + tt * 16 + r16;
        const int k = ck * 32 + kq8;             // 192..287 -> W_hh
        float tmp[8];
        #pragma unroll
        for (int j = 0; j < 8; ++j) tmp[j] = W_hh[(size_t)grow * HID_ + (k - INS_) + j];
        *(short8_t*)&WL[f * 512 + l * 8] = pack8(tmp);
    }
    for (int c = t; c < 16 * XSTR; c += NT) XH[c] = 0;

    // ---- biases (unit u = 32w + 16ti + arow) ----
    float bRr[2], bZr[2], bNXr[2], bNHr[2];
    #pragma unroll
    for (int ti = 0; ti < 2; ++ti) {
        const int u = 32 * wave + 16 * ti + arow;
        bRr[ti]  = b_ih[u] + b_hh[u];
        bZr[ti]  = b_ih[HID_ + u] + b_hh[HID_ + u];
        bNXr[ti] = b_ih[2 * HID_ + u];
        bNHr[ti] = b_hh[2 * HID_ + u];
    }
    const float bdr = (wave < 4) ? b_dec[wave * 16 + arow] : 0.0f;
    float hr[2][4] = {{0.f,0.f,0.f,0.f},{0.f,0.f,0.f,0.f}};
    __syncthreads();

    // ======== 191 sequential GRU steps, all block-local ========
    for (int sg = 1; sg <= 191; ++sg) {
        const int tstep = sg - 1;

        // (A) stage x: enc = num(0..63)+emb(64..95); dec = emb only (fb fills 0..63)
        if (sg <= 96) {
            if (t < 256) {
                const int row = t >> 4, q = t & 15;
                float4 v = *(const float4*)&input_num[((size_t)(bb + row) * TSEQ + tstep) * NUM_ + q * 4];
                ushort4 s = { f2bf(v.x), f2bf(v.y), f2bf(v.z), f2bf(v.w) };
                *(ushort4*)&XH[row * XSTR + q * 4] = s;
            } else if (t < 384) {
                const int e = t - 256, row = e >> 3, q = e & 7;
                const int cat = input_cat[(bb + row) * TSEQ + tstep];
                float4 v = *(const float4*)&emb_table[cat * EMB_ + q * 4];
                ushort4 s = { f2bf(v.x), f2bf(v.y), f2bf(v.z), f2bf(v.w) };
                *(ushort4*)&XH[row * XSTR + NUM_ + q * 4] = s;
            }
        } else if (t < 128) {
            const int row = t >> 3, q = t & 7;
            const int cat = input_cat[(bb + row) * TSEQ + tstep];
            float4 v = *(const float4*)&emb_table[cat * EMB_ + q * 4];
            ushort4 s = { f2bf(v.x), f2bf(v.y), f2bf(v.z), f2bf(v.w) };
            *(ushort4*)&XH[row * XSTR + NUM_ + q * 4] = s;
        }
        __syncthreads();   // B1: x + prev h visible

        // (C) decode: dec proj (WD in WL slots 112..143) + fb write + out store.
        //     NO barrier here -- deferred past the fb-independent gate chunks.
        if (sg > 96 && wave < 4) {
            float4_t acc = {0.f, 0.f, 0.f, 0.f};
            #pragma unroll
            for (int c = 0; c < 8; ++c) {
                short8_t b = *(const short8_t*)&WL[(112 + wave * 8 + c) * 512 + lane * 8];
                short8_t a = *(const short8_t*)&XH[arow * XSTR + INS_ + c * 32 + kq];
                acc = MFMA16(a, b, acc);
            }
            const int cg = wave * 16 + arow, pos = sg - 97;
            #pragma unroll
            for (int i = 0; i < 4; ++i) {
                const int row = quad * 4 + i;
                const float val = acc[i] + bdr;
                XH[row * XSTR + cg] = f2bf(val);
                out[((size_t)(bb + row) * LOUT_ + pos) * NUM_ + cg] = val;
            }
        }

        // ---- gates part A: chunks c2..c10 (fb-independent) ----
        float4_t aR[2]  = {{0.f,0.f,0.f,0.f},{0.f,0.f,0.f,0.f}};
        float4_t aZ[2]  = {{0.f,0.f,0.f,0.f},{0.f,0.f,0.f,0.f}};
        float4_t aNX[2] = {{0.f,0.f,0.f,0.f},{0.f,0.f,0.f,0.f}};
        float4_t aNH[2] = {{0.f,0.f,0.f,0.f},{0.f,0.f,0.f,0.f}};

        // issue stream c9 (+ c8 z,n for decode)
        short8_t s9[6];
        #pragma unroll
        for (int g = 0; g < 3; ++g) {
            s9[g * 2 + 0] = *(const short8_t*)&WSf[(size_t)(32 + g * 16 + tt0) * 512 + lane * 8];
            s9[g * 2 + 1] = *(const short8_t*)&WSf[(size_t)(32 + g * 16 + tt1) * 512 + lane * 8];
        }
        short8_t s8z[2], s8n[2];
        if (sg > 96) {
            s8z[0] = *(const short8_t*)&WSf[(size_t)(tt0) * 512 + lane * 8];
            s8z[1] = *(const short8_t*)&WSf[(size_t)(tt1) * 512 + lane * 8];
            s8n[0] = *(const short8_t*)&WSf[(size_t)(16 + tt0) * 512 + lane * 8];
            s8n[1] = *(const short8_t*)&WSf[(size_t)(16 + tt1) * 512 + lane * 8];
        }

        short8_t a;
        // c2: emb
        a = *(const short8_t*)&XH[arow * XSTR + 64 + kq];
        #pragma unroll
        for (int ti = 0; ti < 2; ++ti) {
            aR[ti] = MFMA16(a, wfr[ti][0][2], aR[ti]);
            aZ[ti] = MFMA16(a, wfr[ti][1][2], aZ[ti]);
            aNX[ti] = MFMA16(a, wfr[ti][2][2], aNX[ti]);
        }
        // c3..c5: h (reg weights)
        #pragma unroll
        for (int kc = 3; kc < 6; ++kc) {
            a = *(const short8_t*)&XH[arow * XSTR + kc * 32 + kq];
            #pragma unroll
            for (int ti = 0; ti < 2; ++ti) {
                aR[ti] = MFMA16(a, wfr[ti][0][kc], aR[ti]);
                aZ[ti] = MFMA16(a, wfr[ti][1][kc], aZ[ti]);
                aNH[ti] = MFMA16(a, wfr[ti][2][kc], aNH[ti]);
            }
        }
        // c6,c7: LDS
        #pragma unroll
        for (int cs = 0; cs < 2; ++cs) {
            a = *(const short8_t*)&XH[arow * XSTR + (6 + cs) * 32 + kq];
            #pragma unroll
            for (int ti = 0; ti < 2; ++ti) {
                const int tt = tt0 + ti;
                short8_t b0 = *(const short8_t*)&WL[(cs * 48 + 0 + tt) * 512 + lane * 8];
                short8_t b1 = *(const short8_t*)&WL[(cs * 48 + 16 + tt) * 512 + lane * 8];
                short8_t b2 = *(const short8_t*)&WL[(cs * 48 + 32 + tt) * 512 + lane * 8];
                aR[ti] = MFMA16(a, b0, aR[ti]);
                aZ[ti] = MFMA16(a, b1, aZ[ti]);
                aNH[ti] = MFMA16(a, b2, aNH[ti]);
            }
        }
        // c8: r from LDS always; z,n from LDS (enc) or stream (dec)
        a = *(const short8_t*)&XH[arow * XSTR + 8 * 32 + kq];
        if (sg <= 96) {
            #pragma unroll
            for (int ti = 0; ti < 2; ++ti) {
                const int tt = tt0 + ti;
                short8_t br = *(const short8_t*)&WL[(96 + tt) * 512 + lane * 8];
                short8_t bz = *(const short8_t*)&WL[(112 + tt) * 512 + lane * 8];
                short8_t bn = *(const short8_t*)&WL[(128 + tt) * 512 + lane * 8];
                aR[ti] = MFMA16(a, br, aR[ti]);
                aZ[ti] = MFMA16(a, bz, aZ[ti]);
                aNH[ti] = MFMA16(a, bn, aNH[ti]);
            }
        } else {
            #pragma unroll
            for (int ti = 0; ti < 2; ++ti) {
                const int tt = tt0 + ti;
                short8_t br = *(const short8_t*)&WL[(96 + tt) * 512 + lane * 8];
                aR[ti] = MFMA16(a, br, aR[ti]);
                aZ[ti] = MFMA16(a, s8z[ti], aZ[ti]);
                aNH[ti] = MFMA16(a, s8n[ti], aNH[ti]);
            }
        }
        // issue stream c10
        short8_t s10[6];
        #pragma unroll
        for (int g = 0; g < 3; ++g) {
            s10[g * 2 + 0] = *(const short8_t*)&WSf[(size_t)(80 + g * 16 + tt0) * 512 + lane * 8];
            s10[g * 2 + 1] = *(const short8_t*)&WSf[(size_t)(80 + g * 16 + tt1) * 512 + lane * 8];
        }
        // c9, c10: consume streamed frags
        a = *(const short8_t*)&XH[arow * XSTR + 9 * 32 + kq];
        #pragma unroll
        for (int ti = 0; ti < 2; ++ti) {
            aR[ti] = MFMA16(a, s9[0 * 2 + ti], aR[ti]);
            aZ[ti] = MFMA16(a, s9[1 * 2 + ti], aZ[ti]);
            aNH[ti] = MFMA16(a, s9[2 * 2 + ti], aNH[ti]);
        }
        a = *(const short8_t*)&XH[arow * XSTR + 10 * 32 + kq];
        #pragma unroll
        for (int ti = 0; ti < 2; ++ti) {
            aR[ti] = MFMA16(a, s10[0 * 2 + ti], aR[ti]);
            aZ[ti] = MFMA16(a, s10[1 * 2 + ti], aZ[ti]);
            aNH[ti] = MFMA16(a, s10[2 * 2 + ti], aNH[ti]);
        }

        // B2 (decode only): fb visible; wait overlapped with part-A work above
        if (sg > 96) __syncthreads();

        // ---- gates part B: chunks c0,c1 (num or fb) ----
        a = *(const short8_t*)&XH[arow * XSTR + kq];
        #pragma unroll
        for (int ti = 0; ti < 2; ++ti) {
            aR[ti] = MFMA16(a, wfr[ti][0][0], aR[ti]);
            aZ[ti] = MFMA16(a, wfr[ti][1][0], aZ[ti]);
            aNX[ti] = MFMA16(a, wfr[ti][2][0], aNX[ti]);
        }
        a = *(const short8_t*)&XH[arow * XSTR + 32 + kq];
        #pragma unroll
        for (int ti = 0; ti < 2; ++ti) {
            aR[ti] = MFMA16(a, wfr[ti][0][1], aR[ti]);
            aZ[ti] = MFMA16(a, wfr[ti][1][1], aZ[ti]);
            aNX[ti] = MFMA16(a, wfr[ti][2][1], aNX[ti]);
        }

        // ---- pointwise (rcp/exp2) ----
        #pragma unroll
        for (int ti = 0; ti < 2; ++ti) {
            #pragma unroll
            for (int i = 0; i < 4; ++i) {
                const float r = sigm(aR[ti][i] + bRr[ti]);
                const float z = sigm(aZ[ti][i] + bZr[ti]);
                const float n = tanhx(aNX[ti][i] + bNXr[ti] + r * (aNH[ti][i] + bNHr[ti]));
                hr[ti][i] = (1.0f - z) * n + z * hr[ti][i];
            }
        }

        __syncthreads();   // B3: all waves done reading XH h-cols + WL
        #pragma unroll
        for (int ti = 0; ti < 2; ++ti) {
            #pragma unroll
            for (int i = 0; i < 4; ++i)
                XH[(quad * 4 + i) * XSTR + INS_ + 32 * wave + 16 * ti + arow] = f2bf(hr[ti][i]);
        }

        // ---- boundary: after last encoder step, build WD into WL slots 112..143 ----
        if (sg == 96) {
            for (int i = t; i < 32 * 64; i += NT) {
                const int f = i >> 6, l = i & 63;
                const int w = f >> 3, c = f & 7;
                const int urow = w * 16 + (l & 15), k = c * 32 + (l >> 4) * 8;
                float tmp[8];
                #pragma unroll
                for (int j = 0; j < 8; ++j) tmp[j] = W_dec[(size_t)urow * HID_ + k + j];
                *(short8_t*)&WL[(112 + f) * 512 + l * 8] = pack8(tmp);
            }
            // visibility guaranteed by next iteration's B1 (__syncthreads)
        }
    }

    // ======== epilogue: out position 95 from h_191 ========
    __syncthreads();
    if (wave < 4) {
        float4_t acc = {0.f, 0.f, 0.f, 0.f};
        #pragma unroll
        for (int c = 0; c < 8; ++c) {
            short8_t b = *(const short8_t*)&WL[(112 + wave * 8 + c) * 512 + lane * 8];
            short8_t a = *(const short8_t*)&XH[arow * XSTR + INS_ + c * 32 + kq];
            acc = MFMA16(a, b, acc);
        }
        const int cg = wave * 16 + arow;
        #pragma unroll
        for (int i = 0; i < 4; ++i) {
            const int row = quad * 4 + i;
            out[((size_t)(bb + row) * LOUT_ + 95) * NUM_ + cg] = acc[i] + bdr;
        }
    }
}

// ============ fallback (v1 logic, known-passing fp32) if ws too small ============
__global__ __launch_bounds__(512) void gru_fallback(
    const float* __restrict__ input_num, const int* __restrict__ input_cat,
    const float* __restrict__ emb_table,
    const float* __restrict__ W_ih, const float* __restrict__ W_hh,
    const float* __restrict__ b_ih, const float* __restrict__ b_hh,
    const float* __restrict__ W_dec, const float* __restrict__ b_dec,
    float* __restrict__ out)
{
    __shared__ __align__(16) float xh[4][352];
    __shared__ float wdec[NUM_ * 257];
    const int t = threadIdx.x, bbase = blockIdx.x * 4;
    const int u = t & 255, rb = (t >> 8) * 2;
    for (int i = t; i < NUM_ * HID_; i += 512) wdec[(i >> 8) * 257 + (i & 255)] = W_dec[i];
    for (int i = t; i < 4 * HID_; i += 512) xh[i >> 8][INS_ + (i & 255)] = 0.0f;
    const float bR = b_ih[u] + b_hh[u], bZ = b_ih[256 + u] + b_hh[256 + u];
    const float bNX = b_ih[512 + u], bNH = b_hh[512 + u], bD = b_dec[t & 63];
    __syncthreads();
    auto sg_ = [](float x) { return 1.0f / (1.0f + __expf(-x)); };
    auto th_ = [](float x) { return 2.0f / (1.0f + __expf(-2.0f * x)) - 1.0f; };
    auto step = [&]() {
        float aR0 = bR, aR1 = bR, aZ0 = bZ, aZ1 = bZ, aNX0 = bNX, aNX1 = bNX, aNH0 = bNH, aNH1 = bNH;
        const float* x0 = xh[rb]; const float* x1 = xh[rb + 1];
        for (int kb = 0; kb < 88; ++kb) {
            float4 w0, w1, w2; int k4 = kb * 4;
            if (k4 < INS_) {
                w0 = *(const float4*)&W_ih[(size_t)u * INS_ + k4];
                w1 = *(const float4*)&W_ih[(size_t)(256 + u) * INS_ + k4];
                w2 = *(const float4*)&W_ih[(size_t)(512 + u) * INS_ + k4];
            } else {
                int kh = k4 - INS_;
                w0 = *(const float4*)&W_hh[(size_t)u * HID_ + kh];
                w1 = *(const float4*)&W_hh[(size_t)(256 + u) * HID_ + kh];
                w2 = *(const float4*)&W_hh[(size_t)(512 + u) * HID_ + kh];
            }
            float4 a = *(const float4*)&x0[k4], c = *(const float4*)&x1[k4];
            aR0 += w0.x*a.x+w0.y*a.y+w0.z*a.z+w0.w*a.w; aR1 += w0.x*c.x+w0.y*c.y+w0.z*c.z+w0.w*c.w;
            aZ0 += w1.x*a.x+w1.y*a.y+w1.z*a.z+w1.w*a.w; aZ1 += w1.x*c.x+w1.y*c.y+w1.z*c.z+w1.w*c.w;
            if (k4 < INS_) { aNX0 += w2.x*a.x+w2.y*a.y+w2.z*a.z+w2.w*a.w; aNX1 += w2.x*c.x+w2.y*c.y+w2.z*c.z+w2.w*c.w; }
            else           { aNH0 += w2.x*a.x+w2.y*a.y+w2.z*a.z+w2.w*a.w; aNH1 += w2.x*c.x+w2.y*c.y+w2.z*c.z+w2.w*c.w; }
        }
        float h0 = x0[INS_ + u], h1 = x1[INS_ + u];
        __syncthreads();
        { float r = sg_(aR0), z = sg_(aZ0), n = th_(aNX0 + r * aNH0);
          xh[rb][INS_ + u] = (1 - z) * n + z * h0; }
        { float r = sg_(aR1), z = sg_(aZ1), n = th_(aNX1 + r * aNH1);
          xh[rb + 1][INS_ + u] = (1 - z) * n + z * h1; }
        __syncthreads();
    };
    auto project = [&](int pos) {
        if (t < 256) {
            int r = t >> 6, m = t & 63;
            const float* wr = &wdec[m * 257]; const float* hr2 = &xh[r][INS_];
            float acc = bD;
            for (int k = 0; k < HID_; ++k) acc = fmaf(wr[k], hr2[k], acc);
            out[((size_t)(bbase + r) * LOUT_ + pos) * NUM_ + m] = acc;
            xh[r][m] = acc;
        }
    };
    for (int s = 0; s < LIN_; ++s) {
        if (t < 256) { int r = t >> 6, k = t & 63;
            xh[r][k] = input_num[((size_t)(bbase + r) * TSEQ + s) * NUM_ + k]; }
        if (t < 128) { int r = t >> 5, e = t & 31;
            xh[r][NUM_ + e] = emb_table[input_cat[(bbase + r) * TSEQ + s] * EMB_ + e]; }
        __syncthreads();
        step();
    }
    project(0);
    for (int s = 0; s < LOUT_ - 1; ++s) {
        if (t < 128) { int r = t >> 5, e = t & 31;
            xh[r][NUM_ + e] = emb_table[input_cat[(bbase + r) * TSEQ + LIN_ + s] * EMB_ + e]; }
        __syncthreads();
        step();
        project(s + 1);
    }
}

extern "C" void kernel_launch(void* const* d_in, const int* in_sizes, int n_in,
                              void* d_out, int out_size, void* d_ws, size_t ws_size,
                              hipStream_t stream) {
    const float* input_num = (const float*)d_in[0];
    const int*   input_cat = (const int*)d_in[1];
    const float* emb_table = (const float*)d_in[2];
    const float* W_ih      = (const float*)d_in[3];
    const float* W_hh      = (const float*)d_in[4];
    const float* b_ih      = (const float*)d_in[5];
    const float* b_hh      = (const float*)d_in[6];
    const float* W_dec     = (const float*)d_in[7];
    const float* b_dec     = (const float*)d_in[8];
    float* out = (float*)d_out;

    if (ws_size >= WS_NEED) {
        unsigned char* ws = (unsigned char*)d_ws;
        prep_v13<<<32, 256, 0, stream>>>(W_hh, ws);
        gru_v13<<<NBLK, NT, 0, stream>>>(input_num, input_cat, emb_table,
                                         W_ih, W_hh, b_ih, b_hh, W_dec, b_dec, ws, out);
    } else {
        gru_fallback<<<BATCH / 4, 512, 0, stream>>>(input_num, input_cat, emb_table,
                                                    W_ih, W_hh, b_ih, b_hh, W_dec, b_dec, out);
    }
}

// Round 9
// 838.347 us; speedup vs baseline: 1.4066x; 1.4041x over previous
//
#include <hip/hip_runtime.h>

// Seq2SeqRNN v14: v10 (902us dispatch, session best) restored verbatim, with one
// zero-mechanism change: the 191-step loop split into encoder (1..96) and decoder
// (97..191) loops. Per-iteration code is identical (shared lambda); the wave-
// uniform phase branches vanish from the hot bodies. Rounds 6-8 showed every
// mechanism change (lgkm barriers, double-buffer, SGPR bases, LDS re-tenant)
// regresses 100-300us -- v10's clean single-path body is itself the asset.

#define BATCH 512
#define TSEQ  192
#define LIN_  96
#define LOUT_ 96
#define NUM_  64
#define EMB_  32
#define HID_  256
#define INS_  96

#define NBLK  32
#define NT    512          // 8 waves, 2/SIMD -> 256 unified reg budget
#define XSTR  360          // us stride, XH[16][x(96)|h(256)] (v5/v10-proven)

// ws: fragment-linear bf16 images (1024 B per frag; lane l -> bytes l*16..+16)
//  WL (LDS-staged): fid = g*32 + tt*2 + cs   (g<3, tt<16, cs<2 -> chunk 6+cs)  96 frags
//  WS (streamed)  : fid = g*48 + tt*3 + cs   (cs<3 -> chunk 8+cs)             144 frags
//  WD (W_dec)     : fid = tt*8 + c           (tt<4, c<8)                       32 frags
#define WS_WL   0u
#define WS_WS   98304u
#define WS_WD   245760u
#define WS_NEED 278528u

typedef __attribute__((ext_vector_type(8))) short short8_t;
typedef __attribute__((ext_vector_type(4))) float float4_t;
typedef unsigned short us;

__device__ __forceinline__ us f2bf(float x) {
    unsigned u = __builtin_bit_cast(unsigned, x);
    u = (u + 0x7FFFu + ((u >> 16) & 1u)) >> 16;
    return (us)u;
}
__device__ __forceinline__ float sigm(float x) {
    return __builtin_amdgcn_rcpf(1.0f + __builtin_amdgcn_exp2f(-1.44269504f * x));
}
__device__ __forceinline__ float tanhx(float x) {
    return 2.0f * __builtin_amdgcn_rcpf(1.0f + __builtin_amdgcn_exp2f(-2.88539008f * x)) - 1.0f;
}

__device__ __forceinline__ short8_t pack8(const float* v) {
    short8_t s;
    #pragma unroll
    for (int j = 0; j < 8; ++j) s[j] = (short)f2bf(v[j]);
    return s;
}

#define MFMA16(a, b, c) __builtin_amdgcn_mfma_f32_16x16x32_bf16((a), (b), (c), 0, 0, 0)

// ============ prep: fragment-linear bf16 weight images (v10-identical) ============
__global__ void prep_v14(const float* __restrict__ W_hh, const float* __restrict__ W_dec,
                         unsigned char* __restrict__ ws) {
    us* WLi = (us*)(ws + WS_WL);
    us* WSi = (us*)(ws + WS_WS);
    us* WDi = (us*)(ws + WS_WD);
    const int idx = blockIdx.x * 256 + threadIdx.x;
    if (idx >= 272 * 64) return;
    const int f = idx >> 6, l = idx & 63;
    const int r16 = l & 15, kq8 = (l >> 4) * 8;
    float tmp[8];
    if (f < 96) {                  // WL: chunks 6,7 (k 192..255, all W_hh)
        const int g = f >> 5, rem = f & 31, tt = rem >> 1, cs = rem & 1;
        const int grow = g * 256 + tt * 16 + r16;
        const int k = (6 + cs) * 32 + kq8;
        #pragma unroll
        for (int j = 0; j < 8; ++j) tmp[j] = W_hh[(size_t)grow * HID_ + (k - INS_) + j];
        *(short8_t*)(WLi + (size_t)f * 512 + l * 8) = pack8(tmp);
    } else if (f < 240) {          // WS: chunks 8,9,10 (k 256..351, all W_hh)
        const int s = f - 96, g = s / 48, rem = s % 48, tt = rem / 3, cs = rem % 3;
        const int grow = g * 256 + tt * 16 + r16;
        const int k = (8 + cs) * 32 + kq8;
        #pragma unroll
        for (int j = 0; j < 8; ++j) tmp[j] = W_hh[(size_t)grow * HID_ + (k - INS_) + j];
        *(short8_t*)(WSi + (size_t)s * 512 + l * 8) = pack8(tmp);
    } else {                       // WD
        const int f3 = f - 240, tt = f3 >> 3, c = f3 & 7;
        const int urow = tt * 16 + r16, k = c * 32 + kq8;
        #pragma unroll
        for (int j = 0; j < 8; ++j) tmp[j] = W_dec[(size_t)urow * HID_ + k + j];
        *(short8_t*)(WDi + (size_t)f3 * 512 + l * 8) = pack8(tmp);
    }
}

// ============ main: one self-sufficient block per 16 batch rows ============
__global__ __launch_bounds__(NT, 2) void gru_v14(
    const float* __restrict__ input_num, const int* __restrict__ input_cat,
    const float* __restrict__ emb_table,
    const float* __restrict__ W_ih, const float* __restrict__ W_hh,
    const float* __restrict__ b_ih, const float* __restrict__ b_hh,
    const float* __restrict__ b_dec,
    const unsigned char* __restrict__ ws, float* __restrict__ out)
{
    __shared__ __align__(16) us XH[16 * XSTR];     // 11.25 KB
    __shared__ __align__(16) us WLl[96 * 512];     // 96 KB (chunks 6,7)
    __shared__ __align__(16) us WDl[32 * 512];     // 32 KB (W_dec)

    const us* WSf = (const us*)(ws + WS_WS);

    const int t = threadIdx.x, wave = t >> 6, lane = t & 63;
    const int arow = lane & 15, quad = lane >> 4, kq = quad * 8;
    const int bb = blockIdx.x * 16;
    const int tt0 = 2 * wave, tt1 = 2 * wave + 1;

    // ---- one-time: reg gate-weight frags, chunks 0..5 (144 regs, v5/v10-proven) ----
    short8_t wfr[2][3][6];
    #pragma unroll
    for (int ti = 0; ti < 2; ++ti) {
        #pragma unroll
        for (int g3 = 0; g3 < 3; ++g3) {
            const int grow = g3 * HID_ + 32 * wave + 16 * ti + arow;
            #pragma unroll
            for (int kc = 0; kc < 6; ++kc) {
                float tmp[8];
                #pragma unroll
                for (int j2 = 0; j2 < 2; ++j2) {
                    const int k = kc * 32 + kq + j2 * 4;   // < 192; never straddles 96
                    float4 v = (k < INS_)
                        ? *(const float4*)&W_ih[(size_t)grow * INS_ + k]
                        : *(const float4*)&W_hh[(size_t)grow * HID_ + (k - INS_)];
                    tmp[j2 * 4 + 0] = v.x; tmp[j2 * 4 + 1] = v.y;
                    tmp[j2 * 4 + 2] = v.z; tmp[j2 * 4 + 3] = v.w;
                }
                wfr[ti][g3][kc] = pack8(tmp);
            }
        }
    }

    // ---- one-time: LDS staging (fragment-linear copies) + XH zero ----
    {
        const us* WLi = (const us*)(ws + WS_WL);
        const us* WDi = (const us*)(ws + WS_WD);
        for (int c = t; c < 96 * 64; c += NT)
            *(ulonglong2*)&WLl[c * 8] = *(const ulonglong2*)&WLi[c * 8];
        for (int c = t; c < 32 * 64; c += NT)
            *(ulonglong2*)&WDl[c * 8] = *(const ulonglong2*)&WDi[c * 8];
        for (int c = t; c < 16 * XSTR; c += NT) XH[c] = 0;
    }

    // ---- biases (unit u = 32w + 16ti + arow) ----
    float bRr[2], bZr[2], bNXr[2], bNHr[2];
    #pragma unroll
    for (int ti = 0; ti < 2; ++ti) {
        const int u = 32 * wave + 16 * ti + arow;
        bRr[ti]  = b_ih[u] + b_hh[u];
        bZr[ti]  = b_ih[HID_ + u] + b_hh[HID_ + u];
        bNXr[ti] = b_ih[2 * HID_ + u];
        bNHr[ti] = b_hh[2 * HID_ + u];
    }
    const float bdr = (wave < 4) ? b_dec[wave * 16 + arow] : 0.0f;
    float hr[2][4] = {{0.f,0.f,0.f,0.f},{0.f,0.f,0.f,0.f}};
    __syncthreads();

    // ---- shared step core: gates (v10-exact) + pointwise; updates hr ----
    auto step_core = [&]() __attribute__((always_inline)) {
        float4_t aR[2]  = {{0.f,0.f,0.f,0.f},{0.f,0.f,0.f,0.f}};
        float4_t aZ[2]  = {{0.f,0.f,0.f,0.f},{0.f,0.f,0.f,0.f}};
        float4_t aNX[2] = {{0.f,0.f,0.f,0.f},{0.f,0.f,0.f,0.f}};
        float4_t aNH[2] = {{0.f,0.f,0.f,0.f},{0.f,0.f,0.f,0.f}};

        // issue stream group 1: chunks 8,9 x 3 gates x both tiles (12 loads)
        short8_t s8[6], s9[6];   // [g*2 + ti]
        #pragma unroll
        for (int g = 0; g < 3; ++g) {
            s8[g * 2 + 0] = *(const short8_t*)&WSf[(size_t)(g * 48 + tt0 * 3 + 0) * 512 + lane * 8];
            s8[g * 2 + 1] = *(const short8_t*)&WSf[(size_t)(g * 48 + tt1 * 3 + 0) * 512 + lane * 8];
            s9[g * 2 + 0] = *(const short8_t*)&WSf[(size_t)(g * 48 + tt0 * 3 + 1) * 512 + lane * 8];
            s9[g * 2 + 1] = *(const short8_t*)&WSf[(size_t)(g * 48 + tt1 * 3 + 1) * 512 + lane * 8];
        }

        // chunks 0..5: reg weights (c0,c1=x, c2=emb, c3..5=h); A read ONCE per chunk
        #pragma unroll
        for (int kc = 0; kc < 6; ++kc) {
            short8_t a = *(const short8_t*)&XH[arow * XSTR + kc * 32 + kq];
            #pragma unroll
            for (int ti = 0; ti < 2; ++ti) {
                aR[ti] = MFMA16(a, wfr[ti][0][kc], aR[ti]);
                aZ[ti] = MFMA16(a, wfr[ti][1][kc], aZ[ti]);
                if (kc < 3) aNX[ti] = MFMA16(a, wfr[ti][2][kc], aNX[ti]);
                else        aNH[ti] = MFMA16(a, wfr[ti][2][kc], aNH[ti]);
            }
        }
        // chunks 6,7: LDS (fragment-linear, conflict-free)
        #pragma unroll
        for (int cs = 0; cs < 2; ++cs) {
            short8_t a = *(const short8_t*)&XH[arow * XSTR + (6 + cs) * 32 + kq];
            #pragma unroll
            for (int ti = 0; ti < 2; ++ti) {
                const int tt = tt0 + ti;
                short8_t b0 = *(const short8_t*)&WLl[(0 * 32 + tt * 2 + cs) * 512 + lane * 8];
                short8_t b1 = *(const short8_t*)&WLl[(1 * 32 + tt * 2 + cs) * 512 + lane * 8];
                short8_t b2 = *(const short8_t*)&WLl[(2 * 32 + tt * 2 + cs) * 512 + lane * 8];
                aR[ti] = MFMA16(a, b0, aR[ti]);
                aZ[ti] = MFMA16(a, b1, aZ[ti]);
                aNH[ti] = MFMA16(a, b2, aNH[ti]);
            }
        }
        // issue stream group 2: chunk 10 (6 loads)
        short8_t s10[6];
        #pragma unroll
        for (int g = 0; g < 3; ++g) {
            s10[g * 2 + 0] = *(const short8_t*)&WSf[(size_t)(g * 48 + tt0 * 3 + 2) * 512 + lane * 8];
            s10[g * 2 + 1] = *(const short8_t*)&WSf[(size_t)(g * 48 + tt1 * 3 + 2) * 512 + lane * 8];
        }
        // chunks 8,9,10: consume streamed frags
        {
            short8_t a = *(const short8_t*)&XH[arow * XSTR + 8 * 32 + kq];
            #pragma unroll
            for (int ti = 0; ti < 2; ++ti) {
                aR[ti] = MFMA16(a, s8[0 * 2 + ti], aR[ti]);
                aZ[ti] = MFMA16(a, s8[1 * 2 + ti], aZ[ti]);
                aNH[ti] = MFMA16(a, s8[2 * 2 + ti], aNH[ti]);
            }
            a = *(const short8_t*)&XH[arow * XSTR + 9 * 32 + kq];
            #pragma unroll
            for (int ti = 0; ti < 2; ++ti) {
                aR[ti] = MFMA16(a, s9[0 * 2 + ti], aR[ti]);
                aZ[ti] = MFMA16(a, s9[1 * 2 + ti], aZ[ti]);
                aNH[ti] = MFMA16(a, s9[2 * 2 + ti], aNH[ti]);
            }
            a = *(const short8_t*)&XH[arow * XSTR + 10 * 32 + kq];
            #pragma unroll
            for (int ti = 0; ti < 2; ++ti) {
                aR[ti] = MFMA16(a, s10[0 * 2 + ti], aR[ti]);
                aZ[ti] = MFMA16(a, s10[1 * 2 + ti], aZ[ti]);
                aNH[ti] = MFMA16(a, s10[2 * 2 + ti], aNH[ti]);
            }
        }

        // pointwise GRU cell (rcp/exp2 single-instruction forms)
        #pragma unroll
        for (int ti = 0; ti < 2; ++ti) {
            #pragma unroll
            for (int i = 0; i < 4; ++i) {
                const float r = sigm(aR[ti][i] + bRr[ti]);
                const float z = sigm(aZ[ti][i] + bZr[ti]);
                const float n = tanhx(aNX[ti][i] + bNXr[ti] + r * (aNH[ti][i] + bNHr[ti]));
                hr[ti][i] = (1.0f - z) * n + z * hr[ti][i];
            }
        }
    };
    auto h_write = [&]() __attribute__((always_inline)) {
        #pragma unroll
        for (int ti = 0; ti < 2; ++ti) {
            #pragma unroll
            for (int i = 0; i < 4; ++i)
                XH[(quad * 4 + i) * XSTR + INS_ + 32 * wave + 16 * ti + arow] = f2bf(hr[ti][i]);
        }
    };

    // ======== encoder: 96 steps, branch-free body ========
    for (int sg = 1; sg <= 96; ++sg) {
        const int tstep = sg - 1;
        if (t < 256) {
            const int row = t >> 4, q = t & 15;
            float4 v = *(const float4*)&input_num[((size_t)(bb + row) * TSEQ + tstep) * NUM_ + q * 4];
            ushort4 s = { f2bf(v.x), f2bf(v.y), f2bf(v.z), f2bf(v.w) };
            *(ushort4*)&XH[row * XSTR + q * 4] = s;
        } else if (t < 384) {
            const int e = t - 256, row = e >> 3, q = e & 7;
            const int cat = input_cat[(bb + row) * TSEQ + tstep];
            float4 v = *(const float4*)&emb_table[cat * EMB_ + q * 4];
            ushort4 s = { f2bf(v.x), f2bf(v.y), f2bf(v.z), f2bf(v.w) };
            *(ushort4*)&XH[row * XSTR + NUM_ + q * 4] = s;
        }
        __syncthreads();   // B1: x + prev h visible
        step_core();
        __syncthreads();   // B3: all waves done reading XH h-cols
        h_write();
    }

    // ======== decoder: 95 steps, branch-free body ========
    for (int sg = 97; sg <= 191; ++sg) {
        const int tstep = sg - 1;
        if (t < 128) {
            const int row = t >> 3, q = t & 7;
            const int cat = input_cat[(bb + row) * TSEQ + tstep];
            float4 v = *(const float4*)&emb_table[cat * EMB_ + q * 4];
            ushort4 s = { f2bf(v.x), f2bf(v.y), f2bf(v.z), f2bf(v.w) };
            *(ushort4*)&XH[row * XSTR + NUM_ + q * 4] = s;
        }
        __syncthreads();   // B1: x + prev h visible

        if (wave < 4) {
            float4_t acc = {0.f, 0.f, 0.f, 0.f};
            #pragma unroll
            for (int c = 0; c < 8; ++c) {
                short8_t b = *(const short8_t*)&WDl[(wave * 8 + c) * 512 + lane * 8];
                short8_t a = *(const short8_t*)&XH[arow * XSTR + INS_ + c * 32 + kq];
                acc = MFMA16(a, b, acc);
            }
            const int cg = wave * 16 + arow, pos = sg - 97;
            #pragma unroll
            for (int i = 0; i < 4; ++i) {
                const int row = quad * 4 + i;
                const float val = acc[i] + bdr;
                XH[row * XSTR + cg] = f2bf(val);
                out[((size_t)(bb + row) * LOUT_ + pos) * NUM_ + cg] = val;
            }
        }
        __syncthreads();   // B2: feedback visible

        step_core();
        __syncthreads();   // B3
        h_write();
    }

    // ======== epilogue: out position 95 from h_191 ========
    __syncthreads();
    if (wave < 4) {
        float4_t acc = {0.f, 0.f, 0.f, 0.f};
        #pragma unroll
        for (int c = 0; c < 8; ++c) {
            short8_t b = *(const short8_t*)&WDl[(wave * 8 + c) * 512 + lane * 8];
            short8_t a = *(const short8_t*)&XH[arow * XSTR + INS_ + c * 32 + kq];
            acc = MFMA16(a, b, acc);
        }
        const int cg = wave * 16 + arow;
        #pragma unroll
        for (int i = 0; i < 4; ++i) {
            const int row = quad * 4 + i;
            out[((size_t)(bb + row) * LOUT_ + 95) * NUM_ + cg] = acc[i] + bdr;
        }
    }
}

// ============ fallback (v1 logic, known-passing fp32) if ws too small ============
__global__ __launch_bounds__(512) void gru_fallback(
    const float* __restrict__ input_num, const int* __restrict__ input_cat,
    const float* __restrict__ emb_table,
    const float* __restrict__ W_ih, const float* __restrict__ W_hh,
    const float* __restrict__ b_ih, const float* __restrict__ b_hh,
    const float* __restrict__ W_dec, const float* __restrict__ b_dec,
    float* __restrict__ out)
{
    __shared__ __align__(16) float xh[4][352];
    __shared__ float wdec[NUM_ * 257];
    const int t = threadIdx.x, bbase = blockIdx.x * 4;
    const int u = t & 255, rb = (t >> 8) * 2;
    for (int i = t; i < NUM_ * HID_; i += 512) wdec[(i >> 8) * 257 + (i & 255)] = W_dec[i];
    for (int i = t; i < 4 * HID_; i += 512) xh[i >> 8][INS_ + (i & 255)] = 0.0f;
    const float bR = b_ih[u] + b_hh[u], bZ = b_ih[256 + u] + b_hh[256 + u];
    const float bNX = b_ih[512 + u], bNH = b_hh[512 + u], bD = b_dec[t & 63];
    __syncthreads();
    auto sg_ = [](float x) { return 1.0f / (1.0f + __expf(-x)); };
    auto th_ = [](float x) { return 2.0f / (1.0f + __expf(-2.0f * x)) - 1.0f; };
    auto step = [&]() {
        float aR0 = bR, aR1 = bR, aZ0 = bZ, aZ1 = bZ, aNX0 = bNX, aNX1 = bNX, aNH0 = bNH, aNH1 = bNH;
        const float* x0 = xh[rb]; const float* x1 = xh[rb + 1];
        for (int kb = 0; kb < 88; ++kb) {
            float4 w0, w1, w2; int k4 = kb * 4;
            if (k4 < INS_) {
                w0 = *(const float4*)&W_ih[(size_t)u * INS_ + k4];
                w1 = *(const float4*)&W_ih[(size_t)(256 + u) * INS_ + k4];
                w2 = *(const float4*)&W_ih[(size_t)(512 + u) * INS_ + k4];
            } else {
                int kh = k4 - INS_;
                w0 = *(const float4*)&W_hh[(size_t)u * HID_ + kh];
                w1 = *(const float4*)&W_hh[(size_t)(256 + u) * HID_ + kh];
                w2 = *(const float4*)&W_hh[(size_t)(512 + u) * HID_ + kh];
            }
            float4 a = *(const float4*)&x0[k4], c = *(const float4*)&x1[k4];
            aR0 += w0.x*a.x+w0.y*a.y+w0.z*a.z+w0.w*a.w; aR1 += w0.x*c.x+w0.y*c.y+w0.z*c.z+w0.w*c.w;
            aZ0 += w1.x*a.x+w1.y*a.y+w1.z*a.z+w1.w*a.w; aZ1 += w1.x*c.x+w1.y*c.y+w1.z*c.z+w1.w*c.w;
            if (k4 < INS_) { aNX0 += w2.x*a.x+w2.y*a.y+w2.z*a.z+w2.w*a.w; aNX1 += w2.x*c.x+w2.y*c.y+w2.z*c.z+w2.w*c.w; }
            else           { aNH0 += w2.x*a.x+w2.y*a.y+w2.z*a.z+w2.w*a.w; aNH1 += w2.x*c.x+w2.y*c.y+w2.z*c.z+w2.w*c.w; }
        }
        float h0 = x0[INS_ + u], h1 = x1[INS_ + u];
        __syncthreads();
        { float r = sg_(aR0), z = sg_(aZ0), n = th_(aNX0 + r * aNH0);
          xh[rb][INS_ + u] = (1 - z) * n + z * h0; }
        { float r = sg_(aR1), z = sg_(aZ1), n = th_(aNX1 + r * aNH1);
          xh[rb + 1][INS_ + u] = (1 - z) * n + z * h1; }
        __syncthreads();
    };
    auto project = [&](int pos) {
        if (t < 256) {
            int r = t >> 6, m = t & 63;
            const float* wr = &wdec[m * 257]; const float* hr2 = &xh[r][INS_];
            float acc = bD;
            for (int k = 0; k < HID_; ++k) acc = fmaf(wr[k], hr2[k], acc);
            out[((size_t)(bbase + r) * LOUT_ + pos) * NUM_ + m] = acc;
            xh[r][m] = acc;
        }
    };
    for (int s = 0; s < LIN_; ++s) {
        if (t < 256) { int r = t >> 6, k = t & 63;
            xh[r][k] = input_num[((size_t)(bbase + r) * TSEQ + s) * NUM_ + k]; }
        if (t < 128) { int r = t >> 5, e = t & 31;
            xh[r][NUM_ + e] = emb_table[input_cat[(bbase + r) * TSEQ + s] * EMB_ + e]; }
        __syncthreads();
        step();
    }
    project(0);
    for (int s = 0; s < LOUT_ - 1; ++s) {
        if (t < 128) { int r = t >> 5, e = t & 31;
            xh[r][NUM_ + e] = emb_table[input_cat[(bbase + r) * TSEQ + LIN_ + s] * EMB_ + e]; }
        __syncthreads();
        step();
        project(s + 1);
    }
}

extern "C" void kernel_launch(void* const* d_in, const int* in_sizes, int n_in,
                              void* d_out, int out_size, void* d_ws, size_t ws_size,
                              hipStream_t stream) {
    const float* input_num = (const float*)d_in[0];
    const int*   input_cat = (const int*)d_in[1];
    const float* emb_table = (const float*)d_in[2];
    const float* W_ih      = (const float*)d_in[3];
    const float* W_hh      = (const float*)d_in[4];
    const float* b_ih      = (const float*)d_in[5];
    const float* b_hh      = (const float*)d_in[6];
    const float* W_dec     = (const float*)d_in[7];
    const float* b_dec     = (const float*)d_in[8];
    float* out = (float*)d_out;

    if (ws_size >= WS_NEED) {
        unsigned char* ws = (unsigned char*)d_ws;
        prep_v14<<<68, 256, 0, stream>>>(W_hh, W_dec, ws);
        gru_v14<<<NBLK, NT, 0, stream>>>(input_num, input_cat, emb_table,
                                         W_ih, W_hh, b_ih, b_hh, b_dec, ws, out);
    } else {
        gru_fallback<<<BATCH / 4, 512, 0, stream>>>(input_num, input_cat, emb_table,
                                                    W_ih, W_hh, b_ih, b_hh, W_dec, b_dec, out);
    }
}